// Round 1
// baseline (691.098 us; speedup 1.0000x reference)
//
#include <hip/hip_runtime.h>
#include <stdint.h>

#define T_DIM 1024
#define B_DIM 64
#define I_DIM 512
#define H_DIM 512
#define M_DIM (T_DIM*B_DIM)          // 65536 rows for both GEMMs
#define BH    (B_DIM*H_DIM)          // 32768
#define OUT_OFF ((size_t)M_DIM*H_DIM)  // 33554432 floats, then hiddens (B, 2H)

typedef __bf16 bf16x8 __attribute__((ext_vector_type(8)));
typedef float  f32x4  __attribute__((ext_vector_type(4)));

// ---------- helpers ----------
__device__ __forceinline__ void split1(float x, ushort& h, ushort& l) {
  // x ≈ bf16(h) + bf16(l), RNE both
  uint32_t u  = __builtin_bit_cast(uint32_t, x);
  uint32_t hr = (u + 0x7FFFu + ((u >> 16) & 1u)) >> 16;
  float    hf = __builtin_bit_cast(float, hr << 16);
  float    lo = x - hf;
  uint32_t ul = __builtin_bit_cast(uint32_t, lo);
  uint32_t lr = (ul + 0x7FFFu + ((ul >> 16) & 1u)) >> 16;
  h = (ushort)hr; l = (ushort)lr;
}

#define GLOAD_LDS16(g, l)                                                     \
  __builtin_amdgcn_global_load_lds(                                           \
      (const __attribute__((address_space(1))) void*)(g),                     \
      (__attribute__((address_space(3))) void*)(l), 16, 0, 0)

// ---------- split f32 -> (hi, lo) bf16 planes, float4 vectorized ----------
__global__ __launch_bounds__(256)
void split4_kernel(const float4* __restrict__ src, ushort4* __restrict__ hi,
                   ushort4* __restrict__ lo, int n4) {
  int i = blockIdx.x * blockDim.x + threadIdx.x;
  int stride = gridDim.x * blockDim.x;
  for (; i < n4; i += stride) {
    float4 v = src[i];
    ushort4 h4, l4;
    split1(v.x, h4.x, l4.x);
    split1(v.y, h4.y, l4.y);
    split1(v.z, h4.z, l4.z);
    split1(v.w, h4.w, l4.w);
    hi[i] = h4;
    lo[i] = l4;
  }
}

// ---------- GEMM: C[m,n] = sum_k A[m,k]*W[n,k] + bias[n] ----------
// A = Ahi+Alo (bf16 split planes, M x 512 row-major), W = Whi+Wlo (512 x 512 row-major).
// 128x128 tile, BK=32, 256 threads = 4 waves (2x2 of 64x64), mfma 16x16x32 bf16.
// 3-term split product: hi*hi + hi*lo + lo*hi all into the same accumulator.
// LDS slot swizzle: within each 64B row of 4x16B slots, slot_phys = slot ^ ((r ^ r>>2) & 3),
// applied on the global SOURCE address at stage time and on the ds_read address -> ~2-way conflicts.
__global__ __launch_bounds__(256, 2)
void gemm3_kernel(const ushort* __restrict__ Ahi, const ushort* __restrict__ Alo,
                  const ushort* __restrict__ Whi, const ushort* __restrict__ Wlo,
                  const float*  __restrict__ bias, float* __restrict__ C) {
  __shared__ __align__(16) ushort As_hi[128*32];
  __shared__ __align__(16) ushort As_lo[128*32];
  __shared__ __align__(16) ushort Bs_hi[128*32];
  __shared__ __align__(16) ushort Bs_lo[128*32];

  const int tid  = threadIdx.x;
  const int lane = tid & 63;
  const int w    = tid >> 6;           // wave 0..3
  const int wr   = w >> 1, wc = w & 1; // wave -> 64x64 subtile
  const int bid  = blockIdx.x;
  const int bn   = bid & 3;            // N=512 / BN=128 -> 4
  const int bm   = bid >> 2;           // 512 m-blocks

  f32x4 acc[4][4] = {};

  const int r0 = tid >> 2;   // staging row within 64-row chunk
  const int sp = tid & 3;    // physical 16B slot
  const int lr = lane & 15;  // fragment row-in-16
  const int sl = lane >> 4;  // logical slot (k-offset / 8)

  for (int k0 = 0; k0 < 512; k0 += 32) {
    // ---- stage 4 planes x 2 issues of 4KB via global_load_lds (16B/lane) ----
#pragma unroll
    for (int i = 0; i < 2; ++i) {
      const int r  = i*64 + r0;
      const int sd = sp ^ ((r ^ (r >> 2)) & 3);            // data slot for this phys slot
      const size_t ga = (size_t)(bm*128 + r)*512 + k0 + sd*8;
      const size_t gb = (size_t)(bn*128 + r)*512 + k0 + sd*8;
      const int lofs  = i*2048 + w*512;                    // ushort offset, wave-uniform
      GLOAD_LDS16(Ahi + ga, &As_hi[lofs]);
      GLOAD_LDS16(Alo + ga, &As_lo[lofs]);
      GLOAD_LDS16(Whi + gb, &Bs_hi[lofs]);
      GLOAD_LDS16(Wlo + gb, &Bs_lo[lofs]);
    }
    __syncthreads();

    // ---- fragment loads (ds_read_b128 each) ----
    bf16x8 ah[4], al[4], bh[4], bl[4];
#pragma unroll
    for (int mi = 0; mi < 4; ++mi) {
      const int row = wr*64 + mi*16 + lr;
      const int ph  = sl ^ ((row ^ (row >> 2)) & 3);
      const int idx = row*32 + ph*8;
      ah[mi] = *(const bf16x8*)&As_hi[idx];
      al[mi] = *(const bf16x8*)&As_lo[idx];
    }
#pragma unroll
    for (int ni = 0; ni < 4; ++ni) {
      const int row = wc*64 + ni*16 + lr;
      const int ph  = sl ^ ((row ^ (row >> 2)) & 3);
      const int idx = row*32 + ph*8;
      bh[ni] = *(const bf16x8*)&Bs_hi[idx];
      bl[ni] = *(const bf16x8*)&Bs_lo[idx];
    }

    // ---- MFMA: 3 split terms into one accumulator ----
#pragma unroll
    for (int mi = 0; mi < 4; ++mi)
#pragma unroll
      for (int ni = 0; ni < 4; ++ni) {
        acc[mi][ni] = __builtin_amdgcn_mfma_f32_16x16x32_bf16(ah[mi], bh[ni], acc[mi][ni], 0, 0, 0);
        acc[mi][ni] = __builtin_amdgcn_mfma_f32_16x16x32_bf16(ah[mi], bl[ni], acc[mi][ni], 0, 0, 0);
        acc[mi][ni] = __builtin_amdgcn_mfma_f32_16x16x32_bf16(al[mi], bh[ni], acc[mi][ni], 0, 0, 0);
      }
    __syncthreads();
  }

  // ---- epilogue: C[m, n] = acc + bias[n]; C/D layout: col=lane&15, row=(lane>>4)*4+j ----
  const int cm = bm*128 + wr*64;
  const int cn = bn*128 + wc*64;
#pragma unroll
  for (int mi = 0; mi < 4; ++mi) {
    const int rowb = cm + mi*16 + sl*4;
#pragma unroll
    for (int ni = 0; ni < 4; ++ni) {
      const int col = cn + ni*16 + lr;
      const float bv = bias[col];
#pragma unroll
      for (int j = 0; j < 4; ++j)
        C[(size_t)(rowb + j)*512 + col] = acc[mi][ni][j] + bv;
    }
  }
}

// ---------- recurrence scan: h_t = relu(lin_t + u*h_{t-1}) ----------
// One thread per (b,h) lane, sequential over T. MODE 0: write bf16 split planes
// (next GEMM's A) ; MODE 1: write f32 output. Both write final h into hT (B, 2H layout).
template <int MODE>
__global__ __launch_bounds__(64)
void scan_kernel(const float* __restrict__ lin, const float* __restrict__ u,
                 ushort* __restrict__ yhi, ushort* __restrict__ ylo,
                 float* __restrict__ yf, float* __restrict__ hT) {
  const int i = blockIdx.x * 64 + threadIdx.x;   // 0..BH-1
  const float uv = u[i & (H_DIM - 1)];
  float hv = 0.f;
#pragma unroll 8
  for (int t = 0; t < T_DIM; ++t) {
    const float lv = lin[(size_t)t * BH + i];
    hv = fmaxf(fmaf(uv, hv, lv), 0.f);
    if (MODE == 0) {
      ushort hb, lb;
      split1(hv, hb, lb);
      yhi[(size_t)t * BH + i] = hb;
      ylo[(size_t)t * BH + i] = lb;
    } else {
      yf[(size_t)t * BH + i] = hv;
    }
  }
  hT[(i >> 9) * (2 * H_DIM) + (i & (H_DIM - 1))] = hv;
}

// ---------- launch ----------
extern "C" void kernel_launch(void* const* d_in, const int* in_sizes, int n_in,
                              void* d_out, int out_size, void* d_ws, size_t ws_size,
                              hipStream_t stream) {
  const float* x  = (const float*)d_in[0];
  const float* W0 = (const float*)d_in[1];
  const float* b0 = (const float*)d_in[2];
  const float* u0 = (const float*)d_in[3];
  const float* W1 = (const float*)d_in[4];
  const float* b1 = (const float*)d_in[5];
  const float* u1 = (const float*)d_in[6];
  float* out = (float*)d_out;

  // workspace layout (bytes):
  //   lin   : f32 [65536 x 512]           = 134217728
  //   phi   : bf16 plane [65536 x 512]    =  67108864   (x_hi, then reused as ys0_hi)
  //   plo   : bf16 plane [65536 x 512]    =  67108864
  //   w0hi/w0lo/w1hi/w1lo : 512x512 bf16  =   524288 each
  char* ws = (char*)d_ws;
  float*  lin  = (float*)ws;
  ushort* phi  = (ushort*)(ws + 134217728ull);
  ushort* plo  = (ushort*)(ws + 201326592ull);
  ushort* w0hi = (ushort*)(ws + 268435456ull);
  ushort* w0lo = w0hi + 262144;
  ushort* w1hi = w0lo + 262144;
  ushort* w1lo = w1hi + 262144;

  // 1) split inputs to bf16 hi/lo planes
  split4_kernel<<<2048, 256, 0, stream>>>((const float4*)x,  (ushort4*)phi,  (ushort4*)plo,  M_DIM*I_DIM/4);
  split4_kernel<<<256,  256, 0, stream>>>((const float4*)W0, (ushort4*)w0hi, (ushort4*)w0lo, H_DIM*I_DIM/4);
  split4_kernel<<<256,  256, 0, stream>>>((const float4*)W1, (ushort4*)w1hi, (ushort4*)w1lo, H_DIM*H_DIM/4);

  // 2) lin0 = x @ W0^T + b0
  gemm3_kernel<<<2048, 256, 0, stream>>>(phi, plo, w0hi, w0lo, b0, lin);

  // 3) scan layer 0 -> ys0 split planes (reuse phi/plo) + hT0
  scan_kernel<0><<<BH/64, 64, 0, stream>>>(lin, u0, phi, plo, nullptr, out + OUT_OFF);

  // 4) lin1 = ys0 @ W1^T + b1
  gemm3_kernel<<<2048, 256, 0, stream>>>(phi, plo, w1hi, w1lo, b1, lin);

  // 5) scan layer 1 -> out (T,B,H) + hT1
  scan_kernel<1><<<BH/64, 64, 0, stream>>>(lin, u1, nullptr, nullptr, out, out + OUT_OFF + H_DIM);
}

// Round 4
// 575.780 us; speedup vs baseline: 1.2003x; 1.2003x over previous
//
#include <hip/hip_runtime.h>
#include <stdint.h>

#define T_DIM 1024
#define B_DIM 64
#define I_DIM 512
#define H_DIM 512
#define M_DIM (T_DIM*B_DIM)          // 65536 rows for both GEMMs
#define BH    (B_DIM*H_DIM)          // 32768
#define OUT_OFF ((size_t)M_DIM*H_DIM)  // 33554432 floats, then hiddens (B, 2H)

typedef __bf16 bf16x8 __attribute__((ext_vector_type(8)));
typedef float  f32x4  __attribute__((ext_vector_type(4)));

// ---------- helpers ----------
__device__ __forceinline__ void split1(float x, ushort& h, ushort& l) {
  // x ≈ bf16(h) + bf16(l), RNE both
  uint32_t u  = __builtin_bit_cast(uint32_t, x);
  uint32_t hr = (u + 0x7FFFu + ((u >> 16) & 1u)) >> 16;
  float    hf = __builtin_bit_cast(float, hr << 16);
  float    lo = x - hf;
  uint32_t ul = __builtin_bit_cast(uint32_t, lo);
  uint32_t lr = (ul + 0x7FFFu + ((ul >> 16) & 1u)) >> 16;
  h = (ushort)hr; l = (ushort)lr;
}

#define GLOAD_LDS16(g, l)                                                     \
  __builtin_amdgcn_global_load_lds(                                           \
      (const __attribute__((address_space(1))) void*)(g),                     \
      (__attribute__((address_space(3))) void*)(l), 16, 0, 0)

// ---------- split f32 -> (hi, lo) bf16 planes, float4 vectorized ----------
__global__ __launch_bounds__(256)
void split4_kernel(const float4* __restrict__ src, ushort4* __restrict__ hi,
                   ushort4* __restrict__ lo, int n4) {
  int i = blockIdx.x * blockDim.x + threadIdx.x;
  int stride = gridDim.x * blockDim.x;
  for (; i < n4; i += stride) {
    float4 v = src[i];
    ushort4 h4, l4;
    split1(v.x, h4.x, l4.x);
    split1(v.y, h4.y, l4.y);
    split1(v.z, h4.z, l4.z);
    split1(v.w, h4.w, l4.w);
    hi[i] = h4;
    lo[i] = l4;
  }
}

// ---------- GEMM: C[m,n] = sum_k A[m,k]*W[n,k] + bias[n] ----------
// 128x128 tile, BK=32, 256 threads = 4 waves (2x2 of 64x64), mfma 16x16x32 bf16.
// 3-term split product hi*hi + hi*lo + lo*hi into one accumulator.
// LDS slot swizzle (both-sides): slot_phys = slot ^ ((r ^ r>>2) & 3) applied on
// the global SOURCE address at stage time and on the ds_read address.
__global__ __launch_bounds__(256, 4)
void gemm3_kernel(const ushort* __restrict__ Ahi, const ushort* __restrict__ Alo,
                  const ushort* __restrict__ Whi, const ushort* __restrict__ Wlo,
                  const float*  __restrict__ bias, float* __restrict__ C) {
  __shared__ __align__(16) ushort As_hi[128*32];
  __shared__ __align__(16) ushort As_lo[128*32];
  __shared__ __align__(16) ushort Bs_hi[128*32];
  __shared__ __align__(16) ushort Bs_lo[128*32];

  const int tid  = threadIdx.x;
  const int lane = tid & 63;
  const int w    = tid >> 6;           // wave 0..3
  const int wr   = w >> 1, wc = w & 1; // wave -> 64x64 subtile

  // XCD-aware bijective swizzle: grid=2048, 2048%8==0 -> chunked remap (T1)
  const int bid  = (int)((blockIdx.x & 7) * (gridDim.x >> 3) + (blockIdx.x >> 3));
  const int bn   = bid & 3;            // N=512 / BN=128 -> 4
  const int bm   = bid >> 2;           // 512 m-blocks

  f32x4 acc[4][4] = {};

  const int r0 = tid >> 2;   // staging row within 64-row chunk
  const int sp = tid & 3;    // physical 16B slot
  const int lr = lane & 15;  // fragment row-in-16
  const int sl = lane >> 4;  // logical slot (k-offset / 8)

  for (int k0 = 0; k0 < 512; k0 += 32) {
    // ---- stage 4 planes x 2 issues of 4KB via global_load_lds (16B/lane) ----
#pragma unroll
    for (int i = 0; i < 2; ++i) {
      const int r  = i*64 + r0;
      const int sd = sp ^ ((r ^ (r >> 2)) & 3);            // data slot for this phys slot
      const size_t ga = (size_t)(bm*128 + r)*512 + k0 + sd*8;
      const size_t gb = (size_t)(bn*128 + r)*512 + k0 + sd*8;
      const int lofs  = i*2048 + w*512;                    // ushort offset, wave-uniform
      GLOAD_LDS16(Ahi + ga, &As_hi[lofs]);
      GLOAD_LDS16(Alo + ga, &As_lo[lofs]);
      GLOAD_LDS16(Whi + gb, &Bs_hi[lofs]);
      GLOAD_LDS16(Wlo + gb, &Bs_lo[lofs]);
    }
    __syncthreads();

    // ---- fragment loads (ds_read_b128 each) ----
    bf16x8 ah[4], al[4], bh[4], bl[4];
#pragma unroll
    for (int mi = 0; mi < 4; ++mi) {
      const int row = wr*64 + mi*16 + lr;
      const int ph  = sl ^ ((row ^ (row >> 2)) & 3);
      const int idx = row*32 + ph*8;
      ah[mi] = *(const bf16x8*)&As_hi[idx];
      al[mi] = *(const bf16x8*)&As_lo[idx];
    }
#pragma unroll
    for (int ni = 0; ni < 4; ++ni) {
      const int row = wc*64 + ni*16 + lr;
      const int ph  = sl ^ ((row ^ (row >> 2)) & 3);
      const int idx = row*32 + ph*8;
      bh[ni] = *(const bf16x8*)&Bs_hi[idx];
      bl[ni] = *(const bf16x8*)&Bs_lo[idx];
    }

    // ---- MFMA: 3 split terms into one accumulator ----
#pragma unroll
    for (int mi = 0; mi < 4; ++mi)
#pragma unroll
      for (int ni = 0; ni < 4; ++ni) {
        acc[mi][ni] = __builtin_amdgcn_mfma_f32_16x16x32_bf16(ah[mi], bh[ni], acc[mi][ni], 0, 0, 0);
        acc[mi][ni] = __builtin_amdgcn_mfma_f32_16x16x32_bf16(ah[mi], bl[ni], acc[mi][ni], 0, 0, 0);
        acc[mi][ni] = __builtin_amdgcn_mfma_f32_16x16x32_bf16(al[mi], bh[ni], acc[mi][ni], 0, 0, 0);
      }
    __syncthreads();
  }

  // ---- epilogue: C[m, n] = acc + bias[n]; C/D layout: col=lane&15, row=(lane>>4)*4+j ----
  const int cm = bm*128 + wr*64;
  const int cn = bn*128 + wc*64;
#pragma unroll
  for (int mi = 0; mi < 4; ++mi) {
    const int rowb = cm + mi*16 + sl*4;
#pragma unroll
    for (int ni = 0; ni < 4; ++ni) {
      const int col = cn + ni*16 + lr;
      const float bv = bias[col];
#pragma unroll
      for (int j = 0; j < 4; ++j)
        C[(size_t)(rowb + j)*512 + col] = acc[mi][ni][j] + bv;
    }
  }
}

// ---------- recurrence scan: h_t = relu(lin_t + u*h_{t-1}) ----------
// One thread per (b,h). Memory-parallelism fix: 16-deep double-buffered
// register prefetch (two NAMED buffers, all indices compile-time -> no scratch).
// In-flight = 512 waves x 16 loads x 256 B = 2 MB -> ~5 TB/s (vs 1.5 measured R1).
template <int MODE>
__global__ __launch_bounds__(64)
void scan_kernel(const float* __restrict__ lin, const float* __restrict__ u,
                 ushort* __restrict__ yhi, ushort* __restrict__ ylo,
                 float* __restrict__ yf, float* __restrict__ hT) {
  const int i = blockIdx.x * 64 + threadIdx.x;   // 0..BH-1
  const float uv = u[i & (H_DIM - 1)];
  const float* p = lin + i;
  float hv = 0.f;
  float va[16], vb[16];

#pragma unroll
  for (int j = 0; j < 16; ++j) va[j] = p[(size_t)j * BH];

  for (int t0 = 0; t0 < T_DIM; t0 += 32) {
    // prefetch next 16 while computing va
#pragma unroll
    for (int j = 0; j < 16; ++j) vb[j] = p[(size_t)(t0 + 16 + j) * BH];
#pragma unroll
    for (int j = 0; j < 16; ++j) {
      hv = fmaxf(fmaf(uv, hv, va[j]), 0.f);
      const size_t o = (size_t)(t0 + j) * BH + i;
      if (MODE == 0) {
        ushort hb, lb; split1(hv, hb, lb);
        yhi[o] = hb; ylo[o] = lb;
      } else {
        yf[o] = hv;
      }
    }
    if (t0 + 32 < T_DIM) {
#pragma unroll
      for (int j = 0; j < 16; ++j) va[j] = p[(size_t)(t0 + 32 + j) * BH];
    }
#pragma unroll
    for (int j = 0; j < 16; ++j) {
      hv = fmaxf(fmaf(uv, hv, vb[j]), 0.f);
      const size_t o = (size_t)(t0 + 16 + j) * BH + i;
      if (MODE == 0) {
        ushort hb, lb; split1(hv, hb, lb);
        yhi[o] = hb; ylo[o] = lb;
      } else {
        yf[o] = hv;
      }
    }
  }
  hT[(i >> 9) * (2 * H_DIM) + (i & (H_DIM - 1))] = hv;
}

// ---------- launch ----------
extern "C" void kernel_launch(void* const* d_in, const int* in_sizes, int n_in,
                              void* d_out, int out_size, void* d_ws, size_t ws_size,
                              hipStream_t stream) {
  const float* x  = (const float*)d_in[0];
  const float* W0 = (const float*)d_in[1];
  const float* b0 = (const float*)d_in[2];
  const float* u0 = (const float*)d_in[3];
  const float* W1 = (const float*)d_in[4];
  const float* b1 = (const float*)d_in[5];
  const float* u1 = (const float*)d_in[6];
  float* out = (float*)d_out;

  // workspace layout (bytes):
  //   lin   : f32 [65536 x 512]           = 134217728
  //   phi   : bf16 plane [65536 x 512]    =  67108864   (x_hi, then reused as ys0_hi)
  //   plo   : bf16 plane [65536 x 512]    =  67108864
  //   w0hi/w0lo/w1hi/w1lo : 512x512 bf16  =   524288 each
  char* ws = (char*)d_ws;
  float*  lin  = (float*)ws;
  ushort* phi  = (ushort*)(ws + 134217728ull);
  ushort* plo  = (ushort*)(ws + 201326592ull);
  ushort* w0hi = (ushort*)(ws + 268435456ull);
  ushort* w0lo = w0hi + 262144;
  ushort* w1hi = w0lo + 262144;
  ushort* w1lo = w1hi + 262144;

  // 1) split inputs to bf16 hi/lo planes
  split4_kernel<<<2048, 256, 0, stream>>>((const float4*)x,  (ushort4*)phi,  (ushort4*)plo,  M_DIM*I_DIM/4);
  split4_kernel<<<256,  256, 0, stream>>>((const float4*)W0, (ushort4*)w0hi, (ushort4*)w0lo, H_DIM*I_DIM/4);
  split4_kernel<<<256,  256, 0, stream>>>((const float4*)W1, (ushort4*)w1hi, (ushort4*)w1lo, H_DIM*H_DIM/4);

  // 2) lin0 = x @ W0^T + b0
  gemm3_kernel<<<2048, 256, 0, stream>>>(phi, plo, w0hi, w0lo, b0, lin);

  // 3) scan layer 0 -> ys0 split planes (reuse phi/plo) + hT0
  scan_kernel<0><<<BH/64, 64, 0, stream>>>(lin, u0, phi, plo, nullptr, out + OUT_OFF);

  // 4) lin1 = ys0 @ W1^T + b1
  gemm3_kernel<<<2048, 256, 0, stream>>>(phi, plo, w1hi, w1lo, b1, lin);

  // 5) scan layer 1 -> out (T,B,H) + hT1
  scan_kernel<1><<<BH/64, 64, 0, stream>>>(lin, u1, nullptr, nullptr, out, out + OUT_OFF + H_DIM);
}